// Round 9
// baseline (293.033 us; speedup 1.0000x reference)
//
#include <hip/hip_runtime.h>
#include <hip/hip_fp16.h>

// Problem constants (fixed-size problem)
#define NNODES 100000
#define NEDGES 1600000
#define IN_C   128
#define HID_C  128
#define OUT_C  64

// Padded adjacency: deg ~ Poisson(16); P(deg>=64) ~ 3e-22/node. Overflow
// list keeps exactness for any input.
#define CAP     64
#define OVF_MAX 4096

// R16:
//  - UNFUSE gather1/GEMM2: fusedG's pre-GEMM barrier waits on the slowest
//    node's gather (max of 64 Poisson(16) degrees ~ 2x mean) -> 77.4 us vs
//    64.5 standalone. Gathers are now barrier-free.
//  - CHANNEL-SPLIT gathers with XCD affinity: half = blockIdx&1; round-robin
//    dispatch (blockIdx%8 -> XCD) sends even blocks (channels [0,C/2)) to
//    even XCDs, odd to odd. Each XCD's line-universe halves: predicted
//    gather1 FETCH 198 -> ~150 MB, dur -> ~50 us. (Falsifiable: FETCH flat
//    => mapping assumption wrong, revert.)
//  - binA/binB at 512 threads: binA was 391 blocks x 4 waves = 1.5
//    waves/SIMD (grid-limited TLP, ~30 us for 32 MB of traffic).
//  - Weights pre-transposed to fp16 [n][k] once (prep kernel); GEMM blocks
//    stage via int4 copy (no per-block transpose VALU / strided reads).
#define BUCKET_SHIFT 7
#define BUCKET_NODES 128
#define NB ((NNODES + BUCKET_NODES - 1) / BUCKET_NODES)  // 782
#define BCAP 3072     // expected 2046/bucket (Poisson, ~23 sigma guard)
#define BCNT_STRIDE 16  // one counter per 64B line
#define EB 4096       // edges per binA block
#define NBLK_A ((NEDGES + EB - 1) / EB)  // 391
#define GB ((NNODES + 63) / 64)          // 1563 64-row tiles

typedef __attribute__((ext_vector_type(8))) _Float16 half8;
typedef __attribute__((ext_vector_type(4))) _Float16 half4;
typedef __attribute__((ext_vector_type(4))) float floatx4;

// ---------------------------------------------------------------------------
// Index width handling (int64 per reference vs int32 from JAX default)
// ---------------------------------------------------------------------------
__device__ __forceinline__ long long load_idx(const void* p, long long i, int is64) {
  return is64 ? ((const long long*)p)[i] : (long long)((const int*)p)[i];
}

// zero counters + detect index width + pre-transpose W1/W2 to fp16 [n][k]
__global__ void prep_kernel(const void* eidx, int* flag, int* bcnt,
                            int* ovf_cnt, int* ovfA_cnt,
                            const float* __restrict__ W1,
                            const float* __restrict__ W2,
                            _Float16* __restrict__ Wt1,
                            _Float16* __restrict__ Wt2) {
  int i = blockIdx.x * 256 + threadIdx.x;
  if (i < NB * BCNT_STRIDE) bcnt[i] = 0;
  if (i == 0) { *ovf_cnt = 0; *ovfA_cnt = 0; }
  if (blockIdx.x == 0 && threadIdx.x < 64) {  // wave-uniform branch
    const unsigned* w = (const unsigned*)eidx;
    unsigned v = w[2 * threadIdx.x + 1];
    unsigned long long bad = __ballot(v != 0u);
    if (threadIdx.x == 0) *flag = (bad == 0ull) ? 1 : 0;
  }
  const int stride = gridDim.x * 256;
  for (int t = i; t < IN_C * HID_C; t += stride) {   // Wt1[n][k] = W1[k][n]
    int n = t >> 7, k = t & 127;
    Wt1[t] = (_Float16)W1[k * HID_C + n];
  }
  for (int t = i; t < HID_C * OUT_C; t += stride) {  // Wt2[n][k] = W2[k][n]
    int n = t >> 7, k = t & 127;
    Wt2[t] = (_Float16)W2[k * OUT_C + n];
  }
}

// ===========================================================================
// Pass A (512 thr): per block of EB edges: decode once -> LDS stash + LDS
// histogram -> one bulk reservation per nonempty bucket (padded counters,
// rotated order) -> placement at base[b]+LDS offset.
// ===========================================================================
__global__ __launch_bounds__(512) void binA_kernel(const void* __restrict__ eidx,
                                                   const int* __restrict__ flag,
                                                   int* __restrict__ bcnt,
                                                   unsigned* __restrict__ buf,
                                                   int* __restrict__ ovfA_cnt,
                                                   int2* __restrict__ ovfA) {
  __shared__ unsigned se[EB];        // 16 KB: src | dlocal<<17
  __shared__ unsigned short be[EB];  //  8 KB: bucket id
  __shared__ int hist[NB];
  __shared__ int base[NB];
  __shared__ int ofs[NB];
  const int tid = threadIdx.x;
  const int e0 = blockIdx.x * EB;
  const int e1 = min(e0 + EB, NEDGES);
  const int m = e1 - e0;
  const int is64 = *flag;

  for (int b = tid; b < NB; b += 512) { hist[b] = 0; ofs[b] = 0; }
  __syncthreads();

  // phase 1: single decode pass + stash + histogram
  for (int k = tid; k < m; k += 512) {
    int e = e0 + k;
    int s = (int)load_idx(eidx, e, is64);
    int d = (int)load_idx(eidx, (long long)NEDGES + e, is64);
    int b = d >> BUCKET_SHIFT;
    se[k] = (unsigned)s | ((unsigned)(d & (BUCKET_NODES - 1)) << 17);
    be[k] = (unsigned short)b;
    atomicAdd(&hist[b], 1);
  }
  __syncthreads();

  // phase 2: bulk-reserve (rotated start; padded counters = no line sharing)
  int rot = (blockIdx.x * 131) % NB;
  for (int idx = tid; idx < NB; idx += 512) {
    int b = idx + rot;
    if (b >= NB) b -= NB;
    int h = hist[b];
    if (h > 0) base[b] = atomicAdd(&bcnt[b * BCNT_STRIDE], h);
  }
  __syncthreads();

  // phase 3: place from LDS stash
  for (int k = tid; k < m; k += 512) {
    unsigned u = se[k];
    int b = be[k];
    int ko = atomicAdd(&ofs[b], 1);
    int slot = base[b] + ko;
    if (slot < BCAP) {
      buf[(size_t)b * BCAP + slot] = u;
    } else {
      int p = atomicAdd(ovfA_cnt, 1);
      if (p < OVF_MAX)
        ovfA[p] = make_int2((int)(u & 0x1FFFFu),
                            (b << BUCKET_SHIFT) | (int)(u >> 17));
    }
  }
}

// ===========================================================================
// Pass B (512 thr): one block per bucket; replays its contiguous edge list +
// the (tiny) ovfA spill for its bucket through LDS atomics; writes pad tile,
// cnt, dinv.
// ===========================================================================
__global__ __launch_bounds__(512) void binB_kernel(const int* __restrict__ bcnt,
                                                   const unsigned* __restrict__ buf,
                                                   const int* __restrict__ ovfA_cnt,
                                                   const int2* __restrict__ ovfA,
                                                   int* __restrict__ cnt,
                                                   float* __restrict__ dinv,
                                                   int* __restrict__ pad_csr,
                                                   int* __restrict__ ovf_cnt,
                                                   int2* __restrict__ ovf) {
  __shared__ int pad[BUCKET_NODES * CAP];  // 32 KB
  __shared__ int lcnt[BUCKET_NODES];
  const int b = blockIdx.x;
  const int tid = threadIdx.x;
  const int node0 = b << BUCKET_SHIFT;

  if (tid < BUCKET_NODES) lcnt[tid] = 0;
  __syncthreads();

  const int n = min(bcnt[b * BCNT_STRIDE], BCAP);
  for (int k = tid; k < n; k += 512) {
    unsigned u = buf[(size_t)b * BCAP + k];
    int s = (int)(u & 0x1FFFFu);
    int dl = (int)(u >> 17);
    int slot = atomicAdd(&lcnt[dl], 1);
    if (slot < CAP) {
      pad[dl * CAP + slot] = s;
    } else {
      int p = atomicAdd(ovf_cnt, 1);
      if (p < OVF_MAX) ovf[p] = make_int2(s, node0 + dl);
    }
  }
  // fold in pass-A overflow entries belonging to this bucket (expected 0)
  int na = min(*ovfA_cnt, OVF_MAX);
  for (int t = tid; t < na; t += 512) {
    int2 p = ovfA[t];
    if ((p.y >> BUCKET_SHIFT) == b) {
      int dl = p.y & (BUCKET_NODES - 1);
      int slot = atomicAdd(&lcnt[dl], 1);
      if (slot < CAP) {
        pad[dl * CAP + slot] = p.x;
      } else {
        int q = atomicAdd(ovf_cnt, 1);
        if (q < OVF_MAX) ovf[q] = make_int2(p.x, p.y);
      }
    }
  }
  __syncthreads();

  constexpr int I4PN = CAP / 4;  // int4 per node row (16)
  for (int q = tid; q < BUCKET_NODES * I4PN; q += 512) {
    int dl = q / I4PN;
    int gn = node0 + dl;
    if (gn < NNODES) {
      int c = (q % I4PN) * 4;
      *(int4*)&pad_csr[(size_t)gn * CAP + c] = *(const int4*)&pad[dl * CAP + c];
    }
  }
  if (tid < BUCKET_NODES && node0 + tid < NNODES) {
    int c = lcnt[tid];
    cnt[node0 + tid] = c;
    dinv[node0 + tid] = rsqrtf((float)(c + 1));
  }
}

// ===========================================================================
// GEMM1: h1s[M,128] = fp16( (x[M,128] @ W1) * dinv[row] )  (Wt1 pre-transposed)
// ===========================================================================
__global__ __launch_bounds__(256) void gemm1_kernel(const float* __restrict__ x,
                                                    const _Float16* __restrict__ Wt1,
                                                    const float* __restrict__ dinv,
                                                    _Float16* __restrict__ h1s) {
  constexpr int K = IN_C, N = HID_C, KP = K + 8;  // 136
  __shared__ alignas(16) _Float16 Alds[64 * KP];
  __shared__ alignas(16) _Float16 Wlds[N * KP];
  const int tid = threadIdx.x;
  const int row0 = blockIdx.x * 64;

  // stage Wt1 [n][k] fp16 -> Wlds (int4 copy, k16-fast: uniform groups)
  for (int idx = tid; idx < N * (K / 8); idx += 256) {  // 2048 int4
    int n = idx >> 4, k16 = idx & 15;
    *(int4*)&Wlds[n * KP + k16 * 8] = *(const int4*)&Wt1[n * K + k16 * 8];
  }
  // stage A tile (64 x K fp32) -> Alds fp16
  constexpr int F4PR = K / 4;  // 32
  for (int idx = tid; idx < 64 * F4PR; idx += 256) {
    int lr = idx >> 5;
    int c4 = (idx & 31) * 4;
    int gr = row0 + lr;
    if (gr > NNODES - 1) gr = NNODES - 1;
    float4 v = *(const float4*)&x[(size_t)gr * K + c4];
    half4 h = {(_Float16)v.x, (_Float16)v.y, (_Float16)v.z, (_Float16)v.w};
    *(half4*)&Alds[lr * KP + c4] = h;
  }
  __syncthreads();

  const int w = tid >> 6;
  const int lane = tid & 63;
  const int g = lane >> 4;
  const int mi = lane & 15;
  constexpr int NT = N / 16;  // 8
  floatx4 acc[NT];
#pragma unroll
  for (int t = 0; t < NT; ++t) acc[t] = (floatx4){0.f, 0.f, 0.f, 0.f};
  const _Float16* arow = &Alds[(w * 16 + mi) * KP];
#pragma unroll
  for (int ks = 0; ks < K / 32; ++ks) {
    half8 a = *(const half8*)(arow + ks * 32 + g * 8);
#pragma unroll
    for (int t = 0; t < NT; ++t) {
      half8 b = *(const half8*)&Wlds[(t * 16 + mi) * KP + ks * 32 + g * 8];
      acc[t] = __builtin_amdgcn_mfma_f32_16x16x32_f16(a, b, acc[t], 0, 0, 0);
    }
  }
#pragma unroll
  for (int r = 0; r < 4; ++r) {
    int grow = row0 + w * 16 + 4 * g + r;
    if (grow < NNODES) {
      float s = dinv[grow];
      _Float16* orow = h1s + (size_t)grow * N + mi;
#pragma unroll
      for (int t = 0; t < NT; ++t) orow[t * 16] = (_Float16)(acc[t][r] * s);
    }
  }
}

// ===========================================================================
// GEMM2: h2s[M,64] = fp16( (hidden[M,128] @ W2) * dinv[row] )
// ===========================================================================
__global__ __launch_bounds__(256) void gemm2_kernel(const _Float16* __restrict__ hid,
                                                    const _Float16* __restrict__ Wt2,
                                                    const float* __restrict__ dinv,
                                                    _Float16* __restrict__ h2s) {
  constexpr int K = HID_C, N = OUT_C, KP = K + 8;  // 136
  __shared__ alignas(16) _Float16 Alds[64 * KP];
  __shared__ alignas(16) _Float16 Wlds[N * KP];
  const int tid = threadIdx.x;
  const int row0 = blockIdx.x * 64;

  for (int idx = tid; idx < N * (K / 8); idx += 256) {  // 1024 int4
    int n = idx >> 4, k16 = idx & 15;
    *(int4*)&Wlds[n * KP + k16 * 8] = *(const int4*)&Wt2[n * K + k16 * 8];
  }
  for (int idx = tid; idx < 64 * (K / 8); idx += 256) {  // 1024 int4
    int lr = idx >> 4, k16 = idx & 15;
    int gr = row0 + lr;
    if (gr > NNODES - 1) gr = NNODES - 1;
    *(int4*)&Alds[lr * KP + k16 * 8] =
        *(const int4*)&hid[(size_t)gr * K + k16 * 8];
  }
  __syncthreads();

  const int w = tid >> 6;
  const int lane = tid & 63;
  const int g = lane >> 4;
  const int mi = lane & 15;
  constexpr int NT = N / 16;  // 4
  floatx4 acc[NT];
#pragma unroll
  for (int t = 0; t < NT; ++t) acc[t] = (floatx4){0.f, 0.f, 0.f, 0.f};
  const _Float16* arow = &Alds[(w * 16 + mi) * KP];
#pragma unroll
  for (int ks = 0; ks < K / 32; ++ks) {
    half8 a = *(const half8*)(arow + ks * 32 + g * 8);
#pragma unroll
    for (int t = 0; t < NT; ++t) {
      half8 b = *(const half8*)&Wlds[(t * 16 + mi) * KP + ks * 32 + g * 8];
      acc[t] = __builtin_amdgcn_mfma_f32_16x16x32_f16(a, b, acc[t], 0, 0, 0);
    }
  }
#pragma unroll
  for (int r = 0; r < 4; ++r) {
    int grow = row0 + w * 16 + 4 * g + r;
    if (grow < NNODES) {
      float s = dinv[grow];
      _Float16* orow = h2s + (size_t)grow * N + mi;
#pragma unroll
      for (int t = 0; t < NT; ++t) orow[t * 16] = (_Float16)(acc[t][r] * s);
    }
  }
}

// ---------------------------------------------------------------------------
// Gather over PRE-SCALED fp16 rows Hs[i] = h[i]*dinv[i]:
//   sum = Hs[i] + SUM_j Hs[adj(i,j)];  out = act(di*sum + bias)
// ---------------------------------------------------------------------------
struct F8 {
  float x0, x1, x2, x3, x4, x5, x6, x7;
};

__device__ __forceinline__ void add_h8(F8& a, const __half* p) {
  int4 r = *(const int4*)p;  // 8 halves
  const __half2* h = (const __half2*)&r;
  float2 f0 = __half22float2(h[0]);
  float2 f1 = __half22float2(h[1]);
  float2 f2 = __half22float2(h[2]);
  float2 f3 = __half22float2(h[3]);
  a.x0 += f0.x; a.x1 += f0.y; a.x2 += f1.x; a.x3 += f1.y;
  a.x4 += f2.x; a.x5 += f2.y; a.x6 += f3.x; a.x7 += f3.y;
}

// ===========================================================================
// gather1 (channel-split): half = blockIdx&1 covers channels [half*64,+64).
// 4 lanes/node x 16 ch; 64 nodes/block; barrier-free.
// hidden = fp16(relu(di*(Hs1[i]+SUM Hs1[s]) + b1))   [channels of this half]
// ===========================================================================
__global__ __launch_bounds__(256) void gather1_kernel(
    const int* __restrict__ cnt, const int* __restrict__ pad_csr,
    const float* __restrict__ dinv, const __half* __restrict__ Hs1,
    const float* __restrict__ b1, const int* __restrict__ ovf_cnt,
    const int2* __restrict__ ovf, _Float16* __restrict__ hidden) {
  constexpr int C = HID_C;
  const int half = blockIdx.x & 1;
  const int tile = blockIdx.x >> 1;
  const int il = threadIdx.x >> 2;              // 0..63
  const int c16 = half * 64 + (threadIdx.x & 3) * 16;
  const int i = tile * 64 + il;
  if (i >= NNODES) return;

  const float di = dinv[i];
  const int deg = cnt[i];
  const int beg = i * CAP;
  const int end = beg + min(deg, CAP);
  const int* __restrict__ lst = pad_csr;
  const __half* __restrict__ Hb = Hs1 + c16;

  F8 a0l = {}, a0h = {}, a1l = {}, a1h = {};
  {
    const __half* p = Hb + (size_t)i * C;  // self term (pre-scaled)
    add_h8(a0l, p);
    add_h8(a0h, p + 8);
  }
  int j = beg;
  for (; j + 8 <= end; j += 8) {
    int4 sa = *(const int4*)&lst[j];
    int4 sb = *(const int4*)&lst[j + 4];
    const __half* p0 = Hb + (size_t)sa.x * C;
    const __half* p1 = Hb + (size_t)sa.y * C;
    const __half* p2 = Hb + (size_t)sa.z * C;
    const __half* p3 = Hb + (size_t)sa.w * C;
    add_h8(a0l, p0); add_h8(a0h, p0 + 8);
    add_h8(a1l, p1); add_h8(a1h, p1 + 8);
    add_h8(a0l, p2); add_h8(a0h, p2 + 8);
    add_h8(a1l, p3); add_h8(a1h, p3 + 8);
    const __half* p4 = Hb + (size_t)sb.x * C;
    const __half* p5 = Hb + (size_t)sb.y * C;
    const __half* p6 = Hb + (size_t)sb.z * C;
    const __half* p7 = Hb + (size_t)sb.w * C;
    add_h8(a0l, p4); add_h8(a0h, p4 + 8);
    add_h8(a1l, p5); add_h8(a1h, p5 + 8);
    add_h8(a0l, p6); add_h8(a0h, p6 + 8);
    add_h8(a1l, p7); add_h8(a1h, p7 + 8);
  }
  for (; j + 2 <= end; j += 2) {
    const __half* p0 = Hb + (size_t)lst[j] * C;
    const __half* p1 = Hb + (size_t)lst[j + 1] * C;
    add_h8(a0l, p0); add_h8(a0h, p0 + 8);
    add_h8(a1l, p1); add_h8(a1h, p1 + 8);
  }
  if (j < end) {
    const __half* p0 = Hb + (size_t)lst[j] * C;
    add_h8(a0l, p0); add_h8(a0h, p0 + 8);
  }
  if (deg > CAP) {  // exactness guard; never taken for Poisson(16)
    int nv = min(*ovf_cnt, OVF_MAX);
    for (int t = 0; t < nv; ++t) {
      int2 p = ovf[t];
      if (p.y == i) {
        const __half* q = Hb + (size_t)p.x * C;
        add_h8(a0l, q); add_h8(a0h, q + 8);
      }
    }
  }

  float4 bb0 = *(const float4*)&b1[c16];
  float4 bb1 = *(const float4*)&b1[c16 + 4];
  float4 bb2 = *(const float4*)&b1[c16 + 8];
  float4 bb3 = *(const float4*)&b1[c16 + 12];
  float o0 = fmaf(a0l.x0 + a1l.x0, di, bb0.x);
  float o1 = fmaf(a0l.x1 + a1l.x1, di, bb0.y);
  float o2 = fmaf(a0l.x2 + a1l.x2, di, bb0.z);
  float o3 = fmaf(a0l.x3 + a1l.x3, di, bb0.w);
  float o4 = fmaf(a0l.x4 + a1l.x4, di, bb1.x);
  float o5 = fmaf(a0l.x5 + a1l.x5, di, bb1.y);
  float o6 = fmaf(a0l.x6 + a1l.x6, di, bb1.z);
  float o7 = fmaf(a0l.x7 + a1l.x7, di, bb1.w);
  float o8 = fmaf(a0h.x0 + a1h.x0, di, bb2.x);
  float o9 = fmaf(a0h.x1 + a1h.x1, di, bb2.y);
  float o10 = fmaf(a0h.x2 + a1h.x2, di, bb2.z);
  float o11 = fmaf(a0h.x3 + a1h.x3, di, bb2.w);
  float o12 = fmaf(a0h.x4 + a1h.x4, di, bb3.x);
  float o13 = fmaf(a0h.x5 + a1h.x5, di, bb3.y);
  float o14 = fmaf(a0h.x6 + a1h.x6, di, bb3.z);
  float o15 = fmaf(a0h.x7 + a1h.x7, di, bb3.w);
  o0 = o0 > 0.f ? o0 : 0.f;   o1 = o1 > 0.f ? o1 : 0.f;
  o2 = o2 > 0.f ? o2 : 0.f;   o3 = o3 > 0.f ? o3 : 0.f;
  o4 = o4 > 0.f ? o4 : 0.f;   o5 = o5 > 0.f ? o5 : 0.f;
  o6 = o6 > 0.f ? o6 : 0.f;   o7 = o7 > 0.f ? o7 : 0.f;
  o8 = o8 > 0.f ? o8 : 0.f;   o9 = o9 > 0.f ? o9 : 0.f;
  o10 = o10 > 0.f ? o10 : 0.f; o11 = o11 > 0.f ? o11 : 0.f;
  o12 = o12 > 0.f ? o12 : 0.f; o13 = o13 > 0.f ? o13 : 0.f;
  o14 = o14 > 0.f ? o14 : 0.f; o15 = o15 > 0.f ? o15 : 0.f;

  _Float16* Out = hidden + (size_t)i * C + c16;
  half8 hv0 = {(_Float16)o0, (_Float16)o1, (_Float16)o2, (_Float16)o3,
               (_Float16)o4, (_Float16)o5, (_Float16)o6, (_Float16)o7};
  half8 hv1 = {(_Float16)o8, (_Float16)o9, (_Float16)o10, (_Float16)o11,
               (_Float16)o12, (_Float16)o13, (_Float16)o14, (_Float16)o15};
  *(half8*)Out = hv0;
  *(half8*)(Out + 8) = hv1;
}

// ===========================================================================
// gather2 (channel-split): half = blockIdx&1 covers channels [half*32,+32).
// 2 lanes/node x 16 ch; 128 nodes/block; fp32 out, no relu.
// ===========================================================================
__global__ __launch_bounds__(256) void gather2_kernel(
    const int* __restrict__ cnt, const int* __restrict__ pad_csr,
    const float* __restrict__ dinv, const __half* __restrict__ Hs2,
    const float* __restrict__ b2, const int* __restrict__ ovf_cnt,
    const int2* __restrict__ ovf, float* __restrict__ Out) {
  constexpr int C = OUT_C;
  const int half = blockIdx.x & 1;
  const int tile = blockIdx.x >> 1;
  const int il = threadIdx.x >> 1;              // 0..127
  const int c16 = half * 32 + (threadIdx.x & 1) * 16;
  const int i = tile * 128 + il;
  if (i >= NNODES) return;

  const float di = dinv[i];
  const int deg = cnt[i];
  const int beg = i * CAP;
  const int end = beg + min(deg, CAP);
  const int* __restrict__ lst = pad_csr;
  const __half* __restrict__ Hb = Hs2 + c16;

  F8 a0l = {}, a0h = {}, a1l = {}, a1h = {};
  {
    const __half* p = Hb + (size_t)i * C;
    add_h8(a0l, p);
    add_h8(a0h, p + 8);
  }
  int j = beg;
  for (; j + 8 <= end; j += 8) {
    int4 sa = *(const int4*)&lst[j];
    int4 sb = *(const int4*)&lst[j + 4];
    const __half* p0 = Hb + (size_t)sa.x * C;
    const __half* p1 = Hb + (size_t)sa.y * C;
    const __half* p2 = Hb + (size_t)sa.z * C;
    const __half* p3 = Hb + (size_t)sa.w * C;
    add_h8(a0l, p0); add_h8(a0h, p0 + 8);
    add_h8(a1l, p1); add_h8(a1h, p1 + 8);
    add_h8(a0l, p2); add_h8(a0h, p2 + 8);
    add_h8(a1l, p3); add_h8(a1h, p3 + 8);
    const __half* p4 = Hb + (size_t)sb.x * C;
    const __half* p5 = Hb + (size_t)sb.y * C;
    const __half* p6 = Hb + (size_t)sb.z * C;
    const __half* p7 = Hb + (size_t)sb.w * C;
    add_h8(a0l, p4); add_h8(a0h, p4 + 8);
    add_h8(a1l, p5); add_h8(a1h, p5 + 8);
    add_h8(a0l, p6); add_h8(a0h, p6 + 8);
    add_h8(a1l, p7); add_h8(a1h, p7 + 8);
  }
  for (; j + 2 <= end; j += 2) {
    const __half* p0 = Hb + (size_t)lst[j] * C;
    const __half* p1 = Hb + (size_t)lst[j + 1] * C;
    add_h8(a0l, p0); add_h8(a0h, p0 + 8);
    add_h8(a1l, p1); add_h8(a1h, p1 + 8);
  }
  if (j < end) {
    const __half* p0 = Hb + (size_t)lst[j] * C;
    add_h8(a0l, p0); add_h8(a0h, p0 + 8);
  }
  if (deg > CAP) {
    int nv = min(*ovf_cnt, OVF_MAX);
    for (int t = 0; t < nv; ++t) {
      int2 p = ovf[t];
      if (p.y == i) {
        const __half* q = Hb + (size_t)p.x * C;
        add_h8(a0l, q); add_h8(a0h, q + 8);
      }
    }
  }

  float4 bb0 = *(const float4*)&b2[c16];
  float4 bb1 = *(const float4*)&b2[c16 + 4];
  float4 bb2 = *(const float4*)&b2[c16 + 8];
  float4 bb3 = *(const float4*)&b2[c16 + 12];
  float* O = Out + (size_t)i * C + c16;
  *(float4*)O = make_float4(fmaf(a0l.x0 + a1l.x0, di, bb0.x),
                            fmaf(a0l.x1 + a1l.x1, di, bb0.y),
                            fmaf(a0l.x2 + a1l.x2, di, bb0.z),
                            fmaf(a0l.x3 + a1l.x3, di, bb0.w));
  *(float4*)(O + 4) = make_float4(fmaf(a0l.x4 + a1l.x4, di, bb1.x),
                                  fmaf(a0l.x5 + a1l.x5, di, bb1.y),
                                  fmaf(a0l.x6 + a1l.x6, di, bb1.z),
                                  fmaf(a0l.x7 + a1l.x7, di, bb1.w));
  *(float4*)(O + 8) = make_float4(fmaf(a0h.x0 + a1h.x0, di, bb2.x),
                                  fmaf(a0h.x1 + a1h.x1, di, bb2.y),
                                  fmaf(a0h.x2 + a1h.x2, di, bb2.z),
                                  fmaf(a0h.x3 + a1h.x3, di, bb2.w));
  *(float4*)(O + 12) = make_float4(fmaf(a0h.x4 + a1h.x4, di, bb3.x),
                                   fmaf(a0h.x5 + a1h.x5, di, bb3.y),
                                   fmaf(a0h.x6 + a1h.x6, di, bb3.z),
                                   fmaf(a0h.x7 + a1h.x7, di, bb3.w));
}

// ===========================================================================
// Launch (7 kernels)
// ===========================================================================
extern "C" void kernel_launch(void* const* d_in, const int* in_sizes, int n_in,
                              void* d_out, int out_size, void* d_ws, size_t ws_size,
                              hipStream_t stream) {
  const float* x = (const float*)d_in[0];
  const void* eidx = d_in[1];
  const float* W1 = (const float*)d_in[2];
  const float* b1 = (const float*)d_in[3];
  const float* W2 = (const float*)d_in[4];
  const float* b2 = (const float*)d_in[5];
  float* out = (float*)d_out;
  char* ws = (char*)d_ws;

  // Workspace layout (512B-aligned, ~87.5 MB):
  int*      flag     = (int*)(ws + 0);              //         4 B
  int*      ovf_cnt  = (int*)(ws + 512);            //         4 B
  int*      ovfA_cnt = (int*)(ws + 1024);           //         4 B
  int*      bcnt     = (int*)(ws + 1536);           //    50,048 B (782*16)
  int*      cnt      = (int*)(ws + 52224);          //   400,000 B
  float*    dinv     = (float*)(ws + 452608);       //   400,000 B
  int2*     ovf      = (int2*)(ws + 852992);        //    32,768 B
  int2*     ovfA     = (int2*)(ws + 885760);        //    32,768 B
  _Float16* Wt1      = (_Float16*)(ws + 918528);    //    32,768 B
  _Float16* Wt2      = (_Float16*)(ws + 951296);    //    16,384 B
  unsigned* buf      = (unsigned*)(ws + 968192);    // 9,609,216 B (782*3072*4)
  int*      pad_csr  = (int*)(ws + 10577920);       // 25,600,000 B (100k x 64)
  _Float16* h1s      = (_Float16*)(ws + 36178432);  // 25,600,000 B (scaled)
  _Float16* hidden   = (_Float16*)(ws + 61778944);  // 25,600,000 B
  _Float16* h2s      = h1s;  // h1s dead after gather1; reuse for h2s (12.8 MB)

  prep_kernel<<<(NB * BCNT_STRIDE + 255) / 256, 256, 0, stream>>>(
      eidx, flag, bcnt, ovf_cnt, ovfA_cnt, W1, W2, Wt1, Wt2);
  binA_kernel<<<NBLK_A, 512, 0, stream>>>(eidx, flag, bcnt, buf, ovfA_cnt, ovfA);
  binB_kernel<<<NB, 512, 0, stream>>>(bcnt, buf, ovfA_cnt, ovfA, cnt, dinv,
                                      pad_csr, ovf_cnt, ovf);
  gemm1_kernel<<<GB, 256, 0, stream>>>(x, Wt1, dinv, h1s);
  gather1_kernel<<<2 * GB, 256, 0, stream>>>(cnt, pad_csr, dinv,
                                             (const __half*)h1s, b1,
                                             ovf_cnt, ovf, hidden);
  gemm2_kernel<<<GB, 256, 0, stream>>>(hidden, Wt2, dinv, h2s);
  gather2_kernel<<<2 * ((NNODES + 127) / 128), 256, 0, stream>>>(
      cnt, pad_csr, dinv, (const __half*)h2s, b2, ovf_cnt, ovf, out);
}

// Round 10
// 270.429 us; speedup vs baseline: 1.0836x; 1.0836x over previous
//
#include <hip/hip_runtime.h>
#include <hip/hip_fp16.h>

// Problem constants (fixed-size problem)
#define NNODES 100000
#define NEDGES 1600000
#define IN_C   128
#define HID_C  128
#define OUT_C  64

// Padded adjacency: deg ~ Poisson(16); P(deg>=64) ~ 3e-22/node. Overflow
// list keeps exactness for any input.
#define CAP     64
#define OVF_MAX 4096

// R17: revert channel-split (falsified: gather1 FETCH 198->188 MB only, and
// gather2 doubled to 63.5 us from the second CSR pass; blockIdx&1 -> XCD
// parity affinity does not hold). Restore R13's proven full-C gathers.
// Keep from R16: 512-thr binA/binB, ovfA folded into binB, prep kernel with
// pre-transposed fp16 weights, unfused GEMM2, h1s buffer reuse.
// gather1 floor is measured-structural: FETCH = 8 XCD x 25.6 MB compulsory
// fills at ~3.4 TB/s L3->L2 = ~64 us (two structures, two occupancies, same
// time). fp8 rows would halve the table but break the 2^-9 absmax tolerance.
#define BUCKET_SHIFT 7
#define BUCKET_NODES 128
#define NB ((NNODES + BUCKET_NODES - 1) / BUCKET_NODES)  // 782
#define BCAP 3072     // expected 2046/bucket (Poisson, ~23 sigma guard)
#define BCNT_STRIDE 16  // one counter per 64B line
#define EB 4096       // edges per binA block
#define NBLK_A ((NEDGES + EB - 1) / EB)  // 391
#define GB ((NNODES + 63) / 64)          // 1563 64-row tiles

typedef __attribute__((ext_vector_type(8))) _Float16 half8;
typedef __attribute__((ext_vector_type(4))) _Float16 half4;
typedef __attribute__((ext_vector_type(4))) float floatx4;

// ---------------------------------------------------------------------------
// Index width handling (int64 per reference vs int32 from JAX default)
// ---------------------------------------------------------------------------
__device__ __forceinline__ long long load_idx(const void* p, long long i, int is64) {
  return is64 ? ((const long long*)p)[i] : (long long)((const int*)p)[i];
}

// zero counters + detect index width + pre-transpose W1/W2 to fp16 [n][k]
__global__ void prep_kernel(const void* eidx, int* flag, int* bcnt,
                            int* ovf_cnt, int* ovfA_cnt,
                            const float* __restrict__ W1,
                            const float* __restrict__ W2,
                            _Float16* __restrict__ Wt1,
                            _Float16* __restrict__ Wt2) {
  int i = blockIdx.x * 256 + threadIdx.x;
  if (i < NB * BCNT_STRIDE) bcnt[i] = 0;
  if (i == 0) { *ovf_cnt = 0; *ovfA_cnt = 0; }
  if (blockIdx.x == 0 && threadIdx.x < 64) {  // wave-uniform branch
    const unsigned* w = (const unsigned*)eidx;
    unsigned v = w[2 * threadIdx.x + 1];
    unsigned long long bad = __ballot(v != 0u);
    if (threadIdx.x == 0) *flag = (bad == 0ull) ? 1 : 0;
  }
  const int stride = gridDim.x * 256;
  for (int t = i; t < IN_C * HID_C; t += stride) {   // Wt1[n][k] = W1[k][n]
    int n = t >> 7, k = t & 127;
    Wt1[t] = (_Float16)W1[k * HID_C + n];
  }
  for (int t = i; t < HID_C * OUT_C; t += stride) {  // Wt2[n][k] = W2[k][n]
    int n = t >> 7, k = t & 127;
    Wt2[t] = (_Float16)W2[k * OUT_C + n];
  }
}

// ===========================================================================
// Pass A (512 thr): per block of EB edges: decode once -> LDS stash + LDS
// histogram -> one bulk reservation per nonempty bucket (padded counters,
// rotated order) -> placement at base[b]+LDS offset.
// ===========================================================================
__global__ __launch_bounds__(512) void binA_kernel(const void* __restrict__ eidx,
                                                   const int* __restrict__ flag,
                                                   int* __restrict__ bcnt,
                                                   unsigned* __restrict__ buf,
                                                   int* __restrict__ ovfA_cnt,
                                                   int2* __restrict__ ovfA) {
  __shared__ unsigned se[EB];        // 16 KB: src | dlocal<<17
  __shared__ unsigned short be[EB];  //  8 KB: bucket id
  __shared__ int hist[NB];
  __shared__ int base[NB];
  __shared__ int ofs[NB];
  const int tid = threadIdx.x;
  const int e0 = blockIdx.x * EB;
  const int e1 = min(e0 + EB, NEDGES);
  const int m = e1 - e0;
  const int is64 = *flag;

  for (int b = tid; b < NB; b += 512) { hist[b] = 0; ofs[b] = 0; }
  __syncthreads();

  // phase 1: single decode pass + stash + histogram
  for (int k = tid; k < m; k += 512) {
    int e = e0 + k;
    int s = (int)load_idx(eidx, e, is64);
    int d = (int)load_idx(eidx, (long long)NEDGES + e, is64);
    int b = d >> BUCKET_SHIFT;
    se[k] = (unsigned)s | ((unsigned)(d & (BUCKET_NODES - 1)) << 17);
    be[k] = (unsigned short)b;
    atomicAdd(&hist[b], 1);
  }
  __syncthreads();

  // phase 2: bulk-reserve (rotated start; padded counters = no line sharing)
  int rot = (blockIdx.x * 131) % NB;
  for (int idx = tid; idx < NB; idx += 512) {
    int b = idx + rot;
    if (b >= NB) b -= NB;
    int h = hist[b];
    if (h > 0) base[b] = atomicAdd(&bcnt[b * BCNT_STRIDE], h);
  }
  __syncthreads();

  // phase 3: place from LDS stash
  for (int k = tid; k < m; k += 512) {
    unsigned u = se[k];
    int b = be[k];
    int ko = atomicAdd(&ofs[b], 1);
    int slot = base[b] + ko;
    if (slot < BCAP) {
      buf[(size_t)b * BCAP + slot] = u;
    } else {
      int p = atomicAdd(ovfA_cnt, 1);
      if (p < OVF_MAX)
        ovfA[p] = make_int2((int)(u & 0x1FFFFu),
                            (b << BUCKET_SHIFT) | (int)(u >> 17));
    }
  }
}

// ===========================================================================
// Pass B (512 thr): one block per bucket; replays its contiguous edge list +
// the (tiny) ovfA spill for its bucket through LDS atomics; writes pad tile,
// cnt, dinv.
// ===========================================================================
__global__ __launch_bounds__(512) void binB_kernel(const int* __restrict__ bcnt,
                                                   const unsigned* __restrict__ buf,
                                                   const int* __restrict__ ovfA_cnt,
                                                   const int2* __restrict__ ovfA,
                                                   int* __restrict__ cnt,
                                                   float* __restrict__ dinv,
                                                   int* __restrict__ pad_csr,
                                                   int* __restrict__ ovf_cnt,
                                                   int2* __restrict__ ovf) {
  __shared__ int pad[BUCKET_NODES * CAP];  // 32 KB
  __shared__ int lcnt[BUCKET_NODES];
  const int b = blockIdx.x;
  const int tid = threadIdx.x;
  const int node0 = b << BUCKET_SHIFT;

  if (tid < BUCKET_NODES) lcnt[tid] = 0;
  __syncthreads();

  const int n = min(bcnt[b * BCNT_STRIDE], BCAP);
  for (int k = tid; k < n; k += 512) {
    unsigned u = buf[(size_t)b * BCAP + k];
    int s = (int)(u & 0x1FFFFu);
    int dl = (int)(u >> 17);
    int slot = atomicAdd(&lcnt[dl], 1);
    if (slot < CAP) {
      pad[dl * CAP + slot] = s;
    } else {
      int p = atomicAdd(ovf_cnt, 1);
      if (p < OVF_MAX) ovf[p] = make_int2(s, node0 + dl);
    }
  }
  // fold in pass-A overflow entries belonging to this bucket (expected 0)
  int na = min(*ovfA_cnt, OVF_MAX);
  for (int t = tid; t < na; t += 512) {
    int2 p = ovfA[t];
    if ((p.y >> BUCKET_SHIFT) == b) {
      int dl = p.y & (BUCKET_NODES - 1);
      int slot = atomicAdd(&lcnt[dl], 1);
      if (slot < CAP) {
        pad[dl * CAP + slot] = p.x;
      } else {
        int q = atomicAdd(ovf_cnt, 1);
        if (q < OVF_MAX) ovf[q] = make_int2(p.x, p.y);
      }
    }
  }
  __syncthreads();

  constexpr int I4PN = CAP / 4;  // int4 per node row (16)
  for (int q = tid; q < BUCKET_NODES * I4PN; q += 512) {
    int dl = q / I4PN;
    int gn = node0 + dl;
    if (gn < NNODES) {
      int c = (q % I4PN) * 4;
      *(int4*)&pad_csr[(size_t)gn * CAP + c] = *(const int4*)&pad[dl * CAP + c];
    }
  }
  if (tid < BUCKET_NODES && node0 + tid < NNODES) {
    int c = lcnt[tid];
    cnt[node0 + tid] = c;
    dinv[node0 + tid] = rsqrtf((float)(c + 1));
  }
}

// ===========================================================================
// GEMM1: h1s[M,128] = fp16( (x[M,128] @ W1) * dinv[row] )  (Wt1 pre-transposed)
// ===========================================================================
__global__ __launch_bounds__(256) void gemm1_kernel(const float* __restrict__ x,
                                                    const _Float16* __restrict__ Wt1,
                                                    const float* __restrict__ dinv,
                                                    _Float16* __restrict__ h1s) {
  constexpr int K = IN_C, N = HID_C, KP = K + 8;  // 136
  __shared__ alignas(16) _Float16 Alds[64 * KP];
  __shared__ alignas(16) _Float16 Wlds[N * KP];
  const int tid = threadIdx.x;
  const int row0 = blockIdx.x * 64;

  // stage Wt1 [n][k] fp16 -> Wlds (int4 copy, k16-fast: uniform groups)
  for (int idx = tid; idx < N * (K / 8); idx += 256) {  // 2048 int4
    int n = idx >> 4, k16 = idx & 15;
    *(int4*)&Wlds[n * KP + k16 * 8] = *(const int4*)&Wt1[n * K + k16 * 8];
  }
  // stage A tile (64 x K fp32) -> Alds fp16
  constexpr int F4PR = K / 4;  // 32
  for (int idx = tid; idx < 64 * F4PR; idx += 256) {
    int lr = idx >> 5;
    int c4 = (idx & 31) * 4;
    int gr = row0 + lr;
    if (gr > NNODES - 1) gr = NNODES - 1;
    float4 v = *(const float4*)&x[(size_t)gr * K + c4];
    half4 h = {(_Float16)v.x, (_Float16)v.y, (_Float16)v.z, (_Float16)v.w};
    *(half4*)&Alds[lr * KP + c4] = h;
  }
  __syncthreads();

  const int w = tid >> 6;
  const int lane = tid & 63;
  const int g = lane >> 4;
  const int mi = lane & 15;
  constexpr int NT = N / 16;  // 8
  floatx4 acc[NT];
#pragma unroll
  for (int t = 0; t < NT; ++t) acc[t] = (floatx4){0.f, 0.f, 0.f, 0.f};
  const _Float16* arow = &Alds[(w * 16 + mi) * KP];
#pragma unroll
  for (int ks = 0; ks < K / 32; ++ks) {
    half8 a = *(const half8*)(arow + ks * 32 + g * 8);
#pragma unroll
    for (int t = 0; t < NT; ++t) {
      half8 b = *(const half8*)&Wlds[(t * 16 + mi) * KP + ks * 32 + g * 8];
      acc[t] = __builtin_amdgcn_mfma_f32_16x16x32_f16(a, b, acc[t], 0, 0, 0);
    }
  }
#pragma unroll
  for (int r = 0; r < 4; ++r) {
    int grow = row0 + w * 16 + 4 * g + r;
    if (grow < NNODES) {
      float s = dinv[grow];
      _Float16* orow = h1s + (size_t)grow * N + mi;
#pragma unroll
      for (int t = 0; t < NT; ++t) orow[t * 16] = (_Float16)(acc[t][r] * s);
    }
  }
}

// ===========================================================================
// GEMM2: h2s[M,64] = fp16( (hidden[M,128] @ W2) * dinv[row] )
// ===========================================================================
__global__ __launch_bounds__(256) void gemm2_kernel(const _Float16* __restrict__ hid,
                                                    const _Float16* __restrict__ Wt2,
                                                    const float* __restrict__ dinv,
                                                    _Float16* __restrict__ h2s) {
  constexpr int K = HID_C, N = OUT_C, KP = K + 8;  // 136
  __shared__ alignas(16) _Float16 Alds[64 * KP];
  __shared__ alignas(16) _Float16 Wlds[N * KP];
  const int tid = threadIdx.x;
  const int row0 = blockIdx.x * 64;

  for (int idx = tid; idx < N * (K / 8); idx += 256) {  // 1024 int4
    int n = idx >> 4, k16 = idx & 15;
    *(int4*)&Wlds[n * KP + k16 * 8] = *(const int4*)&Wt2[n * K + k16 * 8];
  }
  for (int idx = tid; idx < 64 * (K / 8); idx += 256) {  // 1024 int4
    int lr = idx >> 4, k16 = idx & 15;
    int gr = row0 + lr;
    if (gr > NNODES - 1) gr = NNODES - 1;
    *(int4*)&Alds[lr * KP + k16 * 8] =
        *(const int4*)&hid[(size_t)gr * K + k16 * 8];
  }
  __syncthreads();

  const int w = tid >> 6;
  const int lane = tid & 63;
  const int g = lane >> 4;
  const int mi = lane & 15;
  constexpr int NT = N / 16;  // 4
  floatx4 acc[NT];
#pragma unroll
  for (int t = 0; t < NT; ++t) acc[t] = (floatx4){0.f, 0.f, 0.f, 0.f};
  const _Float16* arow = &Alds[(w * 16 + mi) * KP];
#pragma unroll
  for (int ks = 0; ks < K / 32; ++ks) {
    half8 a = *(const half8*)(arow + ks * 32 + g * 8);
#pragma unroll
    for (int t = 0; t < NT; ++t) {
      half8 b = *(const half8*)&Wlds[(t * 16 + mi) * KP + ks * 32 + g * 8];
      acc[t] = __builtin_amdgcn_mfma_f32_16x16x32_f16(a, b, acc[t], 0, 0, 0);
    }
  }
#pragma unroll
  for (int r = 0; r < 4; ++r) {
    int grow = row0 + w * 16 + 4 * g + r;
    if (grow < NNODES) {
      float s = dinv[grow];
      _Float16* orow = h2s + (size_t)grow * N + mi;
#pragma unroll
      for (int t = 0; t < NT; ++t) orow[t * 16] = (_Float16)(acc[t][r] * s);
    }
  }
}

// ---------------------------------------------------------------------------
// Gather aggregation over PRE-SCALED fp16 rows Hs[i] = h[i]*dinv[i]:
//   Out[i] = act( dinv[i] * (Hs[i] + sum_j Hs[adj(i,j)]) + bias )
// 16 channels per lane, TPN = C/16 lanes per node. Barrier-free.
// OUT16: write fp16 (hidden); else fp32 (final output).
// ---------------------------------------------------------------------------
struct F8 {
  float x0, x1, x2, x3, x4, x5, x6, x7;
};

__device__ __forceinline__ void add_h8(F8& a, const __half* p) {
  int4 r = *(const int4*)p;  // 8 halves
  const __half2* h = (const __half2*)&r;
  float2 f0 = __half22float2(h[0]);
  float2 f1 = __half22float2(h[1]);
  float2 f2 = __half22float2(h[2]);
  float2 f3 = __half22float2(h[3]);
  a.x0 += f0.x; a.x1 += f0.y; a.x2 += f1.x; a.x3 += f1.y;
  a.x4 += f2.x; a.x5 += f2.y; a.x6 += f3.x; a.x7 += f3.y;
}

template <int C, bool RELU, bool OUT16>
__global__ __launch_bounds__(256) void gather_kernel(const int* __restrict__ cnt,
                                                     const int* __restrict__ pad_csr,
                                                     const float* __restrict__ dinv,
                                                     const __half* __restrict__ Hs,
                                                     const float* __restrict__ bias,
                                                     const int* __restrict__ ovf_cnt,
                                                     const int2* __restrict__ ovf,
                                                     void* __restrict__ OutPtr) {
  constexpr int TPN = C / 16;  // threads per node (8 or 4)
  int gid = blockIdx.x * 256 + threadIdx.x;
  int i = gid / TPN;
  int c16 = (gid % TPN) * 16;
  if (i >= NNODES) return;

  const float di = dinv[i];
  const int deg = cnt[i];
  const int beg = i * CAP;
  const int end = beg + min(deg, CAP);
  const int* __restrict__ lst = pad_csr;
  const __half* __restrict__ Hb = Hs + c16;  // this lane's channel window

  F8 a0l = {}, a0h = {}, a1l = {}, a1h = {};
  {
    const __half* p = Hb + (size_t)i * C;  // self term (pre-scaled)
    add_h8(a0l, p);
    add_h8(a0h, p + 8);
  }

  int j = beg;
  for (; j + 8 <= end; j += 8) {
    // lists are 256B-aligned and j-beg is a multiple of 8 -> int4-aligned
    int4 sa = *(const int4*)&lst[j];
    int4 sb = *(const int4*)&lst[j + 4];
    const __half* p0 = Hb + (size_t)sa.x * C;
    const __half* p1 = Hb + (size_t)sa.y * C;
    const __half* p2 = Hb + (size_t)sa.z * C;
    const __half* p3 = Hb + (size_t)sa.w * C;
    add_h8(a0l, p0); add_h8(a0h, p0 + 8);
    add_h8(a1l, p1); add_h8(a1h, p1 + 8);
    add_h8(a0l, p2); add_h8(a0h, p2 + 8);
    add_h8(a1l, p3); add_h8(a1h, p3 + 8);
    const __half* p4 = Hb + (size_t)sb.x * C;
    const __half* p5 = Hb + (size_t)sb.y * C;
    const __half* p6 = Hb + (size_t)sb.z * C;
    const __half* p7 = Hb + (size_t)sb.w * C;
    add_h8(a0l, p4); add_h8(a0h, p4 + 8);
    add_h8(a1l, p5); add_h8(a1h, p5 + 8);
    add_h8(a0l, p6); add_h8(a0h, p6 + 8);
    add_h8(a1l, p7); add_h8(a1h, p7 + 8);
  }
  for (; j + 2 <= end; j += 2) {
    const __half* p0 = Hb + (size_t)lst[j] * C;
    const __half* p1 = Hb + (size_t)lst[j + 1] * C;
    add_h8(a0l, p0); add_h8(a0h, p0 + 8);
    add_h8(a1l, p1); add_h8(a1h, p1 + 8);
  }
  if (j < end) {
    const __half* p0 = Hb + (size_t)lst[j] * C;
    add_h8(a0l, p0); add_h8(a0h, p0 + 8);
  }

  if (deg > CAP) {  // exactness guard; never taken for Poisson(16) degrees
    int n = min(*ovf_cnt, OVF_MAX);
    for (int t = 0; t < n; ++t) {
      int2 p = ovf[t];
      if (p.y == i) {
        const __half* q = Hb + (size_t)p.x * C;
        add_h8(a0l, q); add_h8(a0h, q + 8);
      }
    }
  }

  float s0 = a0l.x0 + a1l.x0, s1 = a0l.x1 + a1l.x1;
  float s2 = a0l.x2 + a1l.x2, s3 = a0l.x3 + a1l.x3;
  float s4 = a0l.x4 + a1l.x4, s5 = a0l.x5 + a1l.x5;
  float s6 = a0l.x6 + a1l.x6, s7 = a0l.x7 + a1l.x7;
  float s8 = a0h.x0 + a1h.x0, s9 = a0h.x1 + a1h.x1;
  float s10 = a0h.x2 + a1h.x2, s11 = a0h.x3 + a1h.x3;
  float s12 = a0h.x4 + a1h.x4, s13 = a0h.x5 + a1h.x5;
  float s14 = a0h.x6 + a1h.x6, s15 = a0h.x7 + a1h.x7;

  float4 b0 = *(const float4*)&bias[c16];
  float4 b1 = *(const float4*)&bias[c16 + 4];
  float4 b2 = *(const float4*)&bias[c16 + 8];
  float4 b3 = *(const float4*)&bias[c16 + 12];
  float o0 = fmaf(s0, di, b0.x),  o1 = fmaf(s1, di, b0.y);
  float o2 = fmaf(s2, di, b0.z),  o3 = fmaf(s3, di, b0.w);
  float o4 = fmaf(s4, di, b1.x),  o5 = fmaf(s5, di, b1.y);
  float o6 = fmaf(s6, di, b1.z),  o7 = fmaf(s7, di, b1.w);
  float o8 = fmaf(s8, di, b2.x),  o9 = fmaf(s9, di, b2.y);
  float o10 = fmaf(s10, di, b2.z), o11 = fmaf(s11, di, b2.w);
  float o12 = fmaf(s12, di, b3.x), o13 = fmaf(s13, di, b3.y);
  float o14 = fmaf(s14, di, b3.z), o15 = fmaf(s15, di, b3.w);
  if (RELU) {
    o0 = o0 > 0.f ? o0 : 0.f;   o1 = o1 > 0.f ? o1 : 0.f;
    o2 = o2 > 0.f ? o2 : 0.f;   o3 = o3 > 0.f ? o3 : 0.f;
    o4 = o4 > 0.f ? o4 : 0.f;   o5 = o5 > 0.f ? o5 : 0.f;
    o6 = o6 > 0.f ? o6 : 0.f;   o7 = o7 > 0.f ? o7 : 0.f;
    o8 = o8 > 0.f ? o8 : 0.f;   o9 = o9 > 0.f ? o9 : 0.f;
    o10 = o10 > 0.f ? o10 : 0.f; o11 = o11 > 0.f ? o11 : 0.f;
    o12 = o12 > 0.f ? o12 : 0.f; o13 = o13 > 0.f ? o13 : 0.f;
    o14 = o14 > 0.f ? o14 : 0.f; o15 = o15 > 0.f ? o15 : 0.f;
  }
  if (OUT16) {
    _Float16* Out = (_Float16*)OutPtr + (size_t)i * C + c16;
    half8 hv0 = {(_Float16)o0, (_Float16)o1, (_Float16)o2, (_Float16)o3,
                 (_Float16)o4, (_Float16)o5, (_Float16)o6, (_Float16)o7};
    half8 hv1 = {(_Float16)o8, (_Float16)o9, (_Float16)o10, (_Float16)o11,
                 (_Float16)o12, (_Float16)o13, (_Float16)o14, (_Float16)o15};
    *(half8*)Out = hv0;
    *(half8*)(Out + 8) = hv1;
  } else {
    float* Out = (float*)OutPtr + (size_t)i * C + c16;
    *(float4*)Out = make_float4(o0, o1, o2, o3);
    *(float4*)(Out + 4) = make_float4(o4, o5, o6, o7);
    *(float4*)(Out + 8) = make_float4(o8, o9, o10, o11);
    *(float4*)(Out + 12) = make_float4(o12, o13, o14, o15);
  }
}

// ===========================================================================
// Launch (7 kernels)
// ===========================================================================
extern "C" void kernel_launch(void* const* d_in, const int* in_sizes, int n_in,
                              void* d_out, int out_size, void* d_ws, size_t ws_size,
                              hipStream_t stream) {
  const float* x = (const float*)d_in[0];
  const void* eidx = d_in[1];
  const float* W1 = (const float*)d_in[2];
  const float* b1 = (const float*)d_in[3];
  const float* W2 = (const float*)d_in[4];
  const float* b2 = (const float*)d_in[5];
  float* out = (float*)d_out;
  char* ws = (char*)d_ws;

  // Workspace layout (512B-aligned, ~87.5 MB):
  int*      flag     = (int*)(ws + 0);              //         4 B
  int*      ovf_cnt  = (int*)(ws + 512);            //         4 B
  int*      ovfA_cnt = (int*)(ws + 1024);           //         4 B
  int*      bcnt     = (int*)(ws + 1536);           //    50,048 B (782*16)
  int*      cnt      = (int*)(ws + 52224);          //   400,000 B
  float*    dinv     = (float*)(ws + 452608);       //   400,000 B
  int2*     ovf      = (int2*)(ws + 852992);        //    32,768 B
  int2*     ovfA     = (int2*)(ws + 885760);        //    32,768 B
  _Float16* Wt1      = (_Float16*)(ws + 918528);    //    32,768 B
  _Float16* Wt2      = (_Float16*)(ws + 951296);    //    16,384 B
  unsigned* buf      = (unsigned*)(ws + 968192);    // 9,609,216 B (782*3072*4)
  int*      pad_csr  = (int*)(ws + 10577920);       // 25,600,000 B (100k x 64)
  _Float16* h1s      = (_Float16*)(ws + 36178432);  // 25,600,000 B (scaled)
  _Float16* hidden   = (_Float16*)(ws + 61778944);  // 25,600,000 B
  _Float16* h2s      = h1s;  // h1s dead after gather1; reuse for h2s (12.8 MB)

  prep_kernel<<<(NB * BCNT_STRIDE + 255) / 256, 256, 0, stream>>>(
      eidx, flag, bcnt, ovf_cnt, ovfA_cnt, W1, W2, Wt1, Wt2);
  binA_kernel<<<NBLK_A, 512, 0, stream>>>(eidx, flag, bcnt, buf, ovfA_cnt, ovfA);
  binB_kernel<<<NB, 512, 0, stream>>>(bcnt, buf, ovfA_cnt, ovfA, cnt, dinv,
                                      pad_csr, ovf_cnt, ovf);
  gemm1_kernel<<<GB, 256, 0, stream>>>(x, Wt1, dinv, h1s);
  gather_kernel<HID_C, true, true>
      <<<(NNODES * (HID_C / 16) + 255) / 256, 256, 0, stream>>>(
          cnt, pad_csr, dinv, (const __half*)h1s, b1, ovf_cnt, ovf, hidden);
  gemm2_kernel<<<GB, 256, 0, stream>>>(hidden, Wt2, dinv, h2s);
  gather_kernel<OUT_C, false, false>
      <<<(NNODES * (OUT_C / 16) + 255) / 256, 256, 0, stream>>>(
          cnt, pad_csr, dinv, (const __half*)h2s, b2, ovf_cnt, ovf, out);
}